// Round 4
// baseline (2261.291 us; speedup 1.0000x reference)
//
#include <hip/hip_runtime.h>

#define BB 262144
#define TT 20
#define HH 10

static constexpr float L2E = 1.44269504088896340736f;

typedef float v2f __attribute__((ext_vector_type(2)));

__device__ __forceinline__ float frcp(float x)  { return __builtin_amdgcn_rcpf(x); }
__device__ __forceinline__ float fexp2(float x) { return __builtin_amdgcn_exp2f(x); }
__device__ __forceinline__ v2f vfma2(v2f a, v2f b, v2f c) { return __builtin_elementwise_fma(a, b, c); }

// h held in named v2f regs ha..he = (h0,h1),(h2,h3),...,(h8,h9)
#define DOT5(ACC, PTR, BASE) \
    ACC = vfma2(ha, (PTR)[(BASE)+0], ACC); \
    ACC = vfma2(hb, (PTR)[(BASE)+1], ACC); \
    ACC = vfma2(hc, (PTR)[(BASE)+2], ACC); \
    ACC = vfma2(hd, (PTR)[(BASE)+3], ACC); \
    ACC = vfma2(he, (PTR)[(BASE)+4], ACC);

// one LSTM unit: gates -> c update (single rcp) -> h update (LDS-resident weights)
#define UNIT(J, CR, HNR) { \
    v2f ai = {0.f,0.f}, af = {0.f,0.f}, ag = {0.f,0.f}, ao = {0.f,0.f}; \
    DOT5(ai, sWh, (0*HH+(J))*5) \
    DOT5(af, sWh, (1*HH+(J))*5) \
    DOT5(ag, sWh, (2*HH+(J))*5) \
    DOT5(ao, sWh, (3*HH+(J))*5) \
    float gi = ai.x + ai.y + fmaf(x, sWx[0*HH+(J)], sBB[0*HH+(J)]); \
    float gf = af.x + af.y + fmaf(x, sWx[1*HH+(J)], sBB[1*HH+(J)]); \
    float gg = ag.x + ag.y + fmaf(x, sWx[2*HH+(J)], sBB[2*HH+(J)]); \
    float go = ao.x + ao.y + fmaf(x, sWx[3*HH+(J)], sBB[3*HH+(J)]); \
    float ef = fexp2(gf * (-L2E)); \
    float ei = fexp2(gi * (-L2E)); \
    float eg = fexp2(gg * (2.0f*L2E)); \
    float t1 = 1.0f + ef, t2 = 1.0f + ei; \
    float t3 = eg + 1.0f, t4 = eg - 1.0f; \
    float t5 = t2 * t3; \
    float cn = fmaf((CR), t5, t4 * t1) * frcp(t1 * t5); \
    (CR) = cn; \
    float eo = fexp2(go * (-L2E)); \
    float ec = fexp2(cn * (2.0f*L2E)); \
    (HNR) = (ec - 1.0f) * frcp((1.0f + eo) * (ec + 1.0f)); \
}

#define SCOREM(M) { \
    v2f a2 = {0.f,0.f}; \
    DOT5(a2, sW1v, (M)*5) \
    float a = a2.x + a2.y + sHead[M]; \
    a = fmaxf(a, 0.2f * a); \
    z = fmaf(a, sHead[5+(M)], z); \
}

// one time step: score on pre-update h, then LSTM update
#define STEP(X, SREF) { \
    const float x = (X); \
    float z = sHead[10]; \
    SCOREM(0) SCOREM(1) SCOREM(2) SCOREM(3) SCOREM(4) \
    (SREF) = frcp(1.0f + fexp2(z * (-L2E))); \
    v2f na, nb, nc, nd, ne; \
    UNIT(0, cva.x, na.x) UNIT(1, cva.y, na.y) \
    UNIT(2, cvb.x, nb.x) UNIT(3, cvb.y, nb.y) \
    UNIT(4, cvc.x, nc.x) UNIT(5, cvc.y, nc.y) \
    UNIT(6, cvd.x, nd.x) UNIT(7, cvd.y, nd.y) \
    UNIT(8, cve.x, ne.x) UNIT(9, cve.y, ne.y) \
    ha = na; hb = nb; hc = nc; hd = nd; he = ne; \
}

__global__ __launch_bounds__(256, 2) void lstm_disc_kernel(
    const float* __restrict__ values, const float* __restrict__ masks,
    const float* __restrict__ W_ih, const float* __restrict__ W_hh,
    const float* __restrict__ b_ih, const float* __restrict__ b_hh,
    const float* __restrict__ W1, const float* __restrict__ b1,
    const float* __restrict__ W2, const float* __restrict__ b2,
    const int* __restrict__ directp,
    float* __restrict__ out)
{
    __shared__ v2f  sWh[200];    // W_hh: 40 rows x 10, as 5 pairs/row
    __shared__ v2f  sW1v[25];    // W1: 5 rows x 10
    __shared__ float sWx[40];    // W_ih column
    __shared__ float sBB[40];    // b_ih + b_hh
    __shared__ float sHead[12];  // [0..4]=b1, [5..9]=W2, [10]=b2

    const int tid = threadIdx.x;
    if (tid < 200) sWh[tid] = ((const v2f*)W_hh)[tid];
    if (tid < 25)  sW1v[tid] = ((const v2f*)W1)[tid];
    if (tid < 40) { sWx[tid] = W_ih[tid]; sBB[tid] = b_ih[tid] + b_hh[tid]; }
    if (tid < 5)  { sHead[tid] = b1[tid]; sHead[5 + tid] = W2[tid]; }
    if (tid == 0) sHead[10] = b2[0];

    const int b = blockIdx.x * blockDim.x + tid;
    const int dir = *directp;

    // ---- values row into registers (float4, 16B-aligned) ----
    float vals[TT];
    const float4* vrow = reinterpret_cast<const float4*>(values + (size_t)b * TT);
    #pragma unroll
    for (int i = 0; i < TT / 4; ++i) {
        float4 v = vrow[i];
        vals[4 * i + 0] = v.x; vals[4 * i + 1] = v.y;
        vals[4 * i + 2] = v.z; vals[4 * i + 3] = v.w;
    }
    if (dir != 0) {
        #pragma unroll
        for (int i = 0; i < TT / 2; ++i) {
            float tmp = vals[i]; vals[i] = vals[TT - 1 - i]; vals[TT - 1 - i] = tmp;
        }
    }

    // ---- masks pass-through (independent; overlaps with staging/compute) ----
    {
        const float* mrow = masks + (size_t)b * TT;
        float* mout = out + (size_t)BB * TT + (size_t)b * TT;
        if (dir == 0) {
            const float4* m4 = (const float4*)mrow;
            float4* o4 = (float4*)mout;
            #pragma unroll
            for (int i = 0; i < TT / 4; ++i) o4[i] = m4[i];
        } else {
            #pragma unroll
            for (int t = 0; t < TT; ++t) mout[t] = mrow[TT - 1 - t];
        }
    }

    __syncthreads();

    v2f ha = {0.f,0.f}, hb = {0.f,0.f}, hc = {0.f,0.f}, hd = {0.f,0.f}, he = {0.f,0.f};
    v2f cva = {0.f,0.f}, cvb = {0.f,0.f}, cvc = {0.f,0.f}, cvd = {0.f,0.f}, cve = {0.f,0.f};

    float4* s4 = reinterpret_cast<float4*>(out + (size_t)b * TT);
    float sc0 = 0.f, sc1 = 0.f, sc2 = 0.f;

    #pragma unroll
    for (int t = 0; t < TT; ++t) {
        float s;
        STEP(vals[t], s)
        switch (t & 3) {
            case 0: sc0 = s; break;
            case 1: sc1 = s; break;
            case 2: sc2 = s; break;
            case 3: {
                float4 v; v.x = sc0; v.y = sc1; v.z = sc2; v.w = s;
                s4[t >> 2] = v;
                break;
            }
        }
    }
}

extern "C" void kernel_launch(void* const* d_in, const int* in_sizes, int n_in,
                              void* d_out, int out_size, void* d_ws, size_t ws_size,
                              hipStream_t stream) {
    const float* values = (const float*)d_in[0];
    const float* masks  = (const float*)d_in[1];
    const float* W_ih   = (const float*)d_in[2];
    const float* W_hh   = (const float*)d_in[3];
    const float* b_ih   = (const float*)d_in[4];
    const float* b_hh   = (const float*)d_in[5];
    const float* W1     = (const float*)d_in[6];
    const float* b1     = (const float*)d_in[7];
    const float* W2     = (const float*)d_in[8];
    const float* b2     = (const float*)d_in[9];
    const int*   direct = (const int*)d_in[11];
    float* out = (float*)d_out;

    const int block = 256;
    const int grid = (BB + block - 1) / block;
    lstm_disc_kernel<<<grid, block, 0, stream>>>(values, masks, W_ih, W_hh, b_ih, b_hh,
                                                 W1, b1, W2, b2, direct, out);
}

// Round 5
// 207.698 us; speedup vs baseline: 10.8874x; 10.8874x over previous
//
#include <hip/hip_runtime.h>

#define BB 262144
#define TT 20
#define HH 10

static constexpr float L2E = 1.44269504088896340736f;

typedef float v2f __attribute__((ext_vector_type(2)));

__device__ __forceinline__ float frcp(float x)  { return __builtin_amdgcn_rcpf(x); }
__device__ __forceinline__ float fexp2(float x) { return __builtin_amdgcn_exp2f(x); }
__device__ __forceinline__ v2f vfma2(v2f a, v2f b, v2f c) { return __builtin_elementwise_fma(a, b, c); }

// h held in named v2f regs ha..he = (h0,h1),(h2,h3),...,(h8,h9); weights via global
// wave-uniform pointers -> compiler emits s_load (scalar pipe, SGPR-resident).
#define DOT5(ACC, PTR, BASE) \
    ACC = vfma2(ha, (PTR)[(BASE)+0], ACC); \
    ACC = vfma2(hb, (PTR)[(BASE)+1], ACC); \
    ACC = vfma2(hc, (PTR)[(BASE)+2], ACC); \
    ACC = vfma2(hd, (PTR)[(BASE)+3], ACC); \
    ACC = vfma2(he, (PTR)[(BASE)+4], ACC);

// one LSTM unit: gates -> c update (single rcp) -> h update
#define UNIT(J, CR, HNR) { \
    v2f ai = {0.f,0.f}, af = {0.f,0.f}, ag = {0.f,0.f}, ao = {0.f,0.f}; \
    DOT5(ai, Wh2, (0*HH+(J))*5) \
    DOT5(af, Wh2, (1*HH+(J))*5) \
    DOT5(ag, Wh2, (2*HH+(J))*5) \
    DOT5(ao, Wh2, (3*HH+(J))*5) \
    float gi = ai.x + ai.y + fmaf(x, W_ih[0*HH+(J)], bbf[0*HH+(J)]); \
    float gf = af.x + af.y + fmaf(x, W_ih[1*HH+(J)], bbf[1*HH+(J)]); \
    float gg = ag.x + ag.y + fmaf(x, W_ih[2*HH+(J)], bbf[2*HH+(J)]); \
    float go = ao.x + ao.y + fmaf(x, W_ih[3*HH+(J)], bbf[3*HH+(J)]); \
    float ef = fexp2(gf * (-L2E)); \
    float ei = fexp2(gi * (-L2E)); \
    float eg = fexp2(gg * (2.0f*L2E)); \
    float t1 = 1.0f + ef, t2 = 1.0f + ei; \
    float t3 = eg + 1.0f, t4 = eg - 1.0f; \
    float t5 = t2 * t3; \
    float cn = fmaf((CR), t5, t4 * t1) * frcp(t1 * t5); \
    (CR) = cn; \
    float eo = fexp2(go * (-L2E)); \
    float ec = fexp2(cn * (2.0f*L2E)); \
    (HNR) = (ec - 1.0f) * frcp((1.0f + eo) * (ec + 1.0f)); \
}

// t=0 unit: h=0, c=0 -> no matvec, no forget path (cn = tanh(g)*sig(i))
#define UNIT0(J, CR, HNR) { \
    float gi = fmaf(x, W_ih[0*HH+(J)], bbf[0*HH+(J)]); \
    float gg = fmaf(x, W_ih[2*HH+(J)], bbf[2*HH+(J)]); \
    float go = fmaf(x, W_ih[3*HH+(J)], bbf[3*HH+(J)]); \
    float ei = fexp2(gi * (-L2E)); \
    float eg = fexp2(gg * (2.0f*L2E)); \
    float cn = (eg - 1.0f) * frcp((1.0f + ei) * (eg + 1.0f)); \
    (CR) = cn; \
    float eo = fexp2(go * (-L2E)); \
    float ec = fexp2(cn * (2.0f*L2E)); \
    (HNR) = (ec - 1.0f) * frcp((1.0f + eo) * (ec + 1.0f)); \
}

#define SCOREM(M) { \
    v2f a2 = {0.f,0.f}; \
    DOT5(a2, W1v, (M)*5) \
    float a = a2.x + a2.y + b1[M]; \
    a = fmaxf(a, 0.2f * a); \
    z = fmaf(a, W2[M], z); \
}

// one time step: score on pre-update h, then LSTM update
#define STEP(X, SREF) { \
    const float x = (X); \
    float z = b2[0]; \
    SCOREM(0) SCOREM(1) SCOREM(2) SCOREM(3) SCOREM(4) \
    (SREF) = frcp(1.0f + fexp2(z * (-L2E))); \
    v2f na, nb, nc, nd, ne; \
    UNIT(0, cva.x, na.x) UNIT(1, cva.y, na.y) \
    UNIT(2, cvb.x, nb.x) UNIT(3, cvb.y, nb.y) \
    UNIT(4, cvc.x, nc.x) UNIT(5, cvc.y, nc.y) \
    UNIT(6, cvd.x, nd.x) UNIT(7, cvd.y, nd.y) \
    UNIT(8, cve.x, ne.x) UNIT(9, cve.y, ne.y) \
    ha = na; hb = nb; hc = nc; hd = nd; he = ne; \
}

__global__ __launch_bounds__(256, 2) void lstm_disc_kernel(
    const float* __restrict__ values, const float* __restrict__ masks,
    const float* __restrict__ W_ih, const float* __restrict__ W_hh,
    const float* __restrict__ b_ih, const float* __restrict__ b_hh,
    const float* __restrict__ W1, const float* __restrict__ b1,
    const float* __restrict__ W2, const float* __restrict__ b2,
    const int* __restrict__ directp,
    float* __restrict__ out)
{
    const int b = blockIdx.x * blockDim.x + threadIdx.x;
    const int dir = *directp;

    const v2f* __restrict__ Wh2 = (const v2f*)W_hh;   // 200 pairs, wave-uniform
    const v2f* __restrict__ W1v = (const v2f*)W1;     // 25 pairs

    // ---- per-thread inputs first: issue global loads early ----
    float vals[TT];
    const float4* vrow = reinterpret_cast<const float4*>(values + (size_t)b * TT);
    #pragma unroll
    for (int i = 0; i < TT / 4; ++i) {
        float4 v = vrow[i];
        vals[4 * i + 0] = v.x; vals[4 * i + 1] = v.y;
        vals[4 * i + 2] = v.z; vals[4 * i + 3] = v.w;
    }
    if (dir != 0) {
        #pragma unroll
        for (int i = 0; i < TT / 2; ++i) {
            float tmp = vals[i]; vals[i] = vals[TT - 1 - i]; vals[TT - 1 - i] = tmp;
        }
    }

    // ---- masks pass-through (independent store stream) ----
    {
        const float* mrow = masks + (size_t)b * TT;
        float* mout = out + (size_t)BB * TT + (size_t)b * TT;
        if (dir == 0) {
            const float4* m4 = (const float4*)mrow;
            float4* o4 = (float4*)mout;
            #pragma unroll
            for (int i = 0; i < TT / 4; ++i) o4[i] = m4[i];
        } else {
            #pragma unroll
            for (int t = 0; t < TT; ++t) mout[t] = mrow[TT - 1 - t];
        }
    }

    // combined biases: wave-uniform values, constant indices -> SGPRs
    float bbf[4 * HH];
    #pragma unroll
    for (int i = 0; i < 4 * HH; ++i) bbf[i] = b_ih[i] + b_hh[i];

    v2f ha, hb, hc, hd, he;
    v2f cva, cvb, cvc, cvd, cve;

    float4* s4 = reinterpret_cast<float4*>(out + (size_t)b * TT);
    float sc0 = 0.f, sc1 = 0.f, sc2 = 0.f;

    // ---- t = 0 specialized: h=c=0 ----
    {
        // score head on h=0: fully uniform
        float z = b2[0];
        #pragma unroll
        for (int m = 0; m < 5; ++m) {
            float a = b1[m];
            a = fmaxf(a, 0.2f * a);
            z = fmaf(a, W2[m], z);
        }
        sc0 = frcp(1.0f + fexp2(z * (-L2E)));

        const float x = vals[0];
        v2f na, nb, nc, nd, ne;
        UNIT0(0, cva.x, na.x) UNIT0(1, cva.y, na.y)
        UNIT0(2, cvb.x, nb.x) UNIT0(3, cvb.y, nb.y)
        UNIT0(4, cvc.x, nc.x) UNIT0(5, cvc.y, nc.y)
        UNIT0(6, cvd.x, nd.x) UNIT0(7, cvd.y, nd.y)
        UNIT0(8, cve.x, ne.x) UNIT0(9, cve.y, ne.y)
        ha = na; hb = nb; hc = nc; hd = nd; he = ne;
    }

    // ---- t = 1..19 ----
    #pragma unroll
    for (int t = 1; t < TT; ++t) {
        float s;
        STEP(vals[t], s)
        switch (t & 3) {
            case 0: sc0 = s; break;
            case 1: sc1 = s; break;
            case 2: sc2 = s; break;
            case 3: {
                float4 v; v.x = sc0; v.y = sc1; v.z = sc2; v.w = s;
                s4[t >> 2] = v;
                break;
            }
        }
    }
}

extern "C" void kernel_launch(void* const* d_in, const int* in_sizes, int n_in,
                              void* d_out, int out_size, void* d_ws, size_t ws_size,
                              hipStream_t stream) {
    const float* values = (const float*)d_in[0];
    const float* masks  = (const float*)d_in[1];
    const float* W_ih   = (const float*)d_in[2];
    const float* W_hh   = (const float*)d_in[3];
    const float* b_ih   = (const float*)d_in[4];
    const float* b_hh   = (const float*)d_in[5];
    const float* W1     = (const float*)d_in[6];
    const float* b1     = (const float*)d_in[7];
    const float* W2     = (const float*)d_in[8];
    const float* b2     = (const float*)d_in[9];
    const int*   direct = (const int*)d_in[11];
    float* out = (float*)d_out;

    const int block = 256;
    const int grid = (BB + block - 1) / block;
    lstm_disc_kernel<<<grid, block, 0, stream>>>(values, masks, W_ih, W_hh, b_ih, b_hh,
                                                 W1, b1, W2, b2, direct, out);
}

// Round 6
// 203.102 us; speedup vs baseline: 11.1338x; 1.0226x over previous
//
#include <hip/hip_runtime.h>

#define BB 262144
#define TT 20
#define HH 10

static constexpr float L2E = 1.44269504088896340736f;

typedef float v2f __attribute__((ext_vector_type(2)));

__device__ __forceinline__ float frcp(float x)  { return __builtin_amdgcn_rcpf(x); }
__device__ __forceinline__ float fexp2(float x) { return __builtin_amdgcn_exp2f(x); }
__device__ __forceinline__ v2f vfma2(v2f a, v2f b, v2f c) { return __builtin_elementwise_fma(a, b, c); }

// h held in named v2f regs ha..he = (h0,h1),(h2,h3),...,(h8,h9); weights via global
// wave-uniform pointers -> compiler emits s_load (scalar pipe, SGPR-resident).
#define DOT5(ACC, PTR, BASE) \
    ACC = vfma2(ha, (PTR)[(BASE)+0], ACC); \
    ACC = vfma2(hb, (PTR)[(BASE)+1], ACC); \
    ACC = vfma2(hc, (PTR)[(BASE)+2], ACC); \
    ACC = vfma2(hd, (PTR)[(BASE)+3], ACC); \
    ACC = vfma2(he, (PTR)[(BASE)+4], ACC);

// one LSTM unit: gates -> c update (single rcp) -> h update
#define UNIT(J, CR, HNR) { \
    v2f ai = {0.f,0.f}, af = {0.f,0.f}, ag = {0.f,0.f}, ao = {0.f,0.f}; \
    DOT5(ai, Wh2, (0*HH+(J))*5) \
    DOT5(af, Wh2, (1*HH+(J))*5) \
    DOT5(ag, Wh2, (2*HH+(J))*5) \
    DOT5(ao, Wh2, (3*HH+(J))*5) \
    float gi = ai.x + ai.y + fmaf(x, W_ih[0*HH+(J)], bbf[0*HH+(J)]); \
    float gf = af.x + af.y + fmaf(x, W_ih[1*HH+(J)], bbf[1*HH+(J)]); \
    float gg = ag.x + ag.y + fmaf(x, W_ih[2*HH+(J)], bbf[2*HH+(J)]); \
    float go = ao.x + ao.y + fmaf(x, W_ih[3*HH+(J)], bbf[3*HH+(J)]); \
    float ef = fexp2(gf * (-L2E)); \
    float ei = fexp2(gi * (-L2E)); \
    float eg = fexp2(gg * (2.0f*L2E)); \
    float t1 = 1.0f + ef, t2 = 1.0f + ei; \
    float t3 = eg + 1.0f, t4 = eg - 1.0f; \
    float t5 = t2 * t3; \
    float cn = fmaf((CR), t5, t4 * t1) * frcp(t1 * t5); \
    (CR) = cn; \
    float eo = fexp2(go * (-L2E)); \
    float ec = fexp2(cn * (2.0f*L2E)); \
    (HNR) = (ec - 1.0f) * frcp((1.0f + eo) * (ec + 1.0f)); \
}

// t=0 unit: h=0, c=0 -> no matvec, no forget path (cn = tanh(g)*sig(i))
#define UNIT0(J, CR, HNR) { \
    float gi = fmaf(x, W_ih[0*HH+(J)], bbf[0*HH+(J)]); \
    float gg = fmaf(x, W_ih[2*HH+(J)], bbf[2*HH+(J)]); \
    float go = fmaf(x, W_ih[3*HH+(J)], bbf[3*HH+(J)]); \
    float ei = fexp2(gi * (-L2E)); \
    float eg = fexp2(gg * (2.0f*L2E)); \
    float cn = (eg - 1.0f) * frcp((1.0f + ei) * (eg + 1.0f)); \
    (CR) = cn; \
    float eo = fexp2(go * (-L2E)); \
    float ec = fexp2(cn * (2.0f*L2E)); \
    (HNR) = (ec - 1.0f) * frcp((1.0f + eo) * (ec + 1.0f)); \
}

#define SCOREM(M) { \
    v2f a2 = {0.f,0.f}; \
    DOT5(a2, W1v, (M)*5) \
    float a = a2.x + a2.y + b1[M]; \
    a = fmaxf(a, 0.2f * a); \
    z = fmaf(a, W2[M], z); \
}

// one time step: score on pre-update h, then LSTM update
#define STEP(X, SREF) { \
    const float x = (X); \
    float z = b2[0]; \
    SCOREM(0) SCOREM(1) SCOREM(2) SCOREM(3) SCOREM(4) \
    (SREF) = frcp(1.0f + fexp2(z * (-L2E))); \
    v2f na, nb, nc, nd, ne; \
    UNIT(0, cva.x, na.x) UNIT(1, cva.y, na.y) \
    UNIT(2, cvb.x, nb.x) UNIT(3, cvb.y, nb.y) \
    UNIT(4, cvc.x, nc.x) UNIT(5, cvc.y, nc.y) \
    UNIT(6, cvd.x, nd.x) UNIT(7, cvd.y, nd.y) \
    UNIT(8, cve.x, ne.x) UNIT(9, cve.y, ne.y) \
    ha = na; hb = nb; hc = nc; hd = nd; he = ne; \
}

__global__ __launch_bounds__(256)
__attribute__((amdgpu_waves_per_eu(4, 4)))   // grid supplies exactly 4 waves/SIMD;
                                             // pin allocator budget to 512/4 = 128 VGPRs, no spill
void lstm_disc_kernel(
    const float* __restrict__ values, const float* __restrict__ masks,
    const float* __restrict__ W_ih, const float* __restrict__ W_hh,
    const float* __restrict__ b_ih, const float* __restrict__ b_hh,
    const float* __restrict__ W1, const float* __restrict__ b1,
    const float* __restrict__ W2, const float* __restrict__ b2,
    const int* __restrict__ directp,
    float* __restrict__ out)
{
    const int b = blockIdx.x * blockDim.x + threadIdx.x;
    const int dir = *directp;

    const v2f* __restrict__ Wh2 = (const v2f*)W_hh;   // 200 pairs, wave-uniform
    const v2f* __restrict__ W1v = (const v2f*)W1;     // 25 pairs

    // ---- per-thread inputs first: issue global loads early ----
    float vals[TT];
    const float4* vrow = reinterpret_cast<const float4*>(values + (size_t)b * TT);
    #pragma unroll
    for (int i = 0; i < TT / 4; ++i) {
        float4 v = vrow[i];
        vals[4 * i + 0] = v.x; vals[4 * i + 1] = v.y;
        vals[4 * i + 2] = v.z; vals[4 * i + 3] = v.w;
    }
    if (dir != 0) {
        #pragma unroll
        for (int i = 0; i < TT / 2; ++i) {
            float tmp = vals[i]; vals[i] = vals[TT - 1 - i]; vals[TT - 1 - i] = tmp;
        }
    }

    // ---- masks pass-through (independent store stream) ----
    {
        const float* mrow = masks + (size_t)b * TT;
        float* mout = out + (size_t)BB * TT + (size_t)b * TT;
        if (dir == 0) {
            const float4* m4 = (const float4*)mrow;
            float4* o4 = (float4*)mout;
            #pragma unroll
            for (int i = 0; i < TT / 4; ++i) o4[i] = m4[i];
        } else {
            #pragma unroll
            for (int t = 0; t < TT; ++t) mout[t] = mrow[TT - 1 - t];
        }
    }

    // combined biases: wave-uniform values, constant indices -> SGPRs
    float bbf[4 * HH];
    #pragma unroll
    for (int i = 0; i < 4 * HH; ++i) bbf[i] = b_ih[i] + b_hh[i];

    v2f ha, hb, hc, hd, he;
    v2f cva, cvb, cvc, cvd, cve;

    float4* s4 = reinterpret_cast<float4*>(out + (size_t)b * TT);
    float sc0 = 0.f, sc1 = 0.f, sc2 = 0.f;

    // ---- t = 0 specialized: h=c=0 ----
    {
        // score head on h=0: fully uniform
        float z = b2[0];
        #pragma unroll
        for (int m = 0; m < 5; ++m) {
            float a = b1[m];
            a = fmaxf(a, 0.2f * a);
            z = fmaf(a, W2[m], z);
        }
        sc0 = frcp(1.0f + fexp2(z * (-L2E)));

        const float x = vals[0];
        v2f na, nb, nc, nd, ne;
        UNIT0(0, cva.x, na.x) UNIT0(1, cva.y, na.y)
        UNIT0(2, cvb.x, nb.x) UNIT0(3, cvb.y, nb.y)
        UNIT0(4, cvc.x, nc.x) UNIT0(5, cvc.y, nc.y)
        UNIT0(6, cvd.x, nd.x) UNIT0(7, cvd.y, nd.y)
        UNIT0(8, cve.x, ne.x) UNIT0(9, cve.y, ne.y)
        ha = na; hb = nb; hc = nc; hd = nd; he = ne;
    }

    // ---- t = 1..19 ----
    #pragma unroll
    for (int t = 1; t < TT; ++t) {
        float s;
        STEP(vals[t], s)
        switch (t & 3) {
            case 0: sc0 = s; break;
            case 1: sc1 = s; break;
            case 2: sc2 = s; break;
            case 3: {
                float4 v; v.x = sc0; v.y = sc1; v.z = sc2; v.w = s;
                s4[t >> 2] = v;
                break;
            }
        }
    }
}

extern "C" void kernel_launch(void* const* d_in, const int* in_sizes, int n_in,
                              void* d_out, int out_size, void* d_ws, size_t ws_size,
                              hipStream_t stream) {
    const float* values = (const float*)d_in[0];
    const float* masks  = (const float*)d_in[1];
    const float* W_ih   = (const float*)d_in[2];
    const float* W_hh   = (const float*)d_in[3];
    const float* b_ih   = (const float*)d_in[4];
    const float* b_hh   = (const float*)d_in[5];
    const float* W1     = (const float*)d_in[6];
    const float* b1     = (const float*)d_in[7];
    const float* W2     = (const float*)d_in[8];
    const float* b2     = (const float*)d_in[9];
    const int*   direct = (const int*)d_in[11];
    float* out = (float*)d_out;

    const int block = 256;
    const int grid = (BB + block - 1) / block;
    lstm_disc_kernel<<<grid, block, 0, stream>>>(values, masks, W_ih, W_hh, b_ih, b_hh,
                                                 W1, b1, W2, b2, direct, out);
}

// Round 8
// 102.474 us; speedup vs baseline: 22.0669x; 1.9820x over previous
//
#include <hip/hip_runtime.h>

#define BB 262144
#define TT 20
#define HH 10

static constexpr float L2E = 1.44269504088896340736f;

typedef float    f4 __attribute__((ext_vector_type(4)));
typedef _Float16 h4 __attribute__((ext_vector_type(4)));

#define MFMA16(A, B, C) __builtin_amdgcn_mfma_f32_16x16x16f16((A), (B), (C), 0, 0, 0)

__device__ __forceinline__ float frcp(float x)  { return __builtin_amdgcn_rcpf(x); }
__device__ __forceinline__ float fexp2(float x) { return __builtin_amdgcn_exp2f(x); }

// Layout (per wave = 16 sequences, 4 MFMA tiles of 16x16x16 f16):
//   A_tau (weights, preloaded once, 2 VGPR/tile/lane):
//     row r = 4G+e (G=r>>2): unit slot u=4G+tau (u<=9): gate e of unit u
//       k<10: W_hh[10e+u][k]; k==10: b_ih+b_hh[10e+u]; k==11: W_ih[10e+u]
//     head: (G==2,tau==2) rows 8..11 = W1 rows 0..3 (+b1 at k=10)
//           (G==2,tau==3) row  8     = W1 row 4     (+b1[4] at k=10)
//     (G==3,*) zero padding
//   B (per step): k=4g+e, col=s: h[4g+e][s]; g==2 override: k10=1.0, k11=x_t
//   C_tau: lane(g,s) reg r = gate r of unit 4g+tau, seq s  -> lane-local
//   activation; h_new[4g+tau] is exactly this lane's B element e=tau next step.
__global__ __launch_bounds__(256) void lstm_disc_mfma(
    const float* __restrict__ values, const float* __restrict__ masks,
    const float* __restrict__ W_ih, const float* __restrict__ W_hh,
    const float* __restrict__ b_ih, const float* __restrict__ b_hh,
    const float* __restrict__ W1, const float* __restrict__ b1,
    const float* __restrict__ W2, const float* __restrict__ b2,
    const int* __restrict__ directp,
    float* __restrict__ out)
{
    const int tid = threadIdx.x;
    const int l   = tid & 63;
    const int g   = l >> 4;    // k-window group (B/C); A k-window
    const int s   = l & 15;    // seq within wave (B/C col); A row
    const int gw  = blockIdx.x * 4 + (tid >> 6);
    const int seq = gw * 16 + s;
    const int dir = *directp;

    // ---- build A fragments once (per-lane scattered weight loads) ----
    h4 Afrag[4];
    {
        const int r  = s;          // A row = l&15
        const int G  = r >> 2;
        const int eg = r & 3;      // gate index (unit slots) / head row
        const int kb = g * 4;      // k-window base
        #pragma unroll
        for (int tau = 0; tau < 4; ++tau) {
            float av0 = 0.f, av1 = 0.f, av2 = 0.f, av3 = 0.f;
            float* avp[4] = {&av0, &av1, &av2, &av3};
            #pragma unroll
            for (int e = 0; e < 4; ++e) {
                const int k = kb + e;
                const int u = 4 * G + tau;
                float v = 0.0f;
                if (G <= 2 && u <= 9) {                    // LSTM unit slot
                    const int orow = 10 * eg + u;          // gate eg, unit u
                    if (k < 10)       v = W_hh[orow * 10 + k];
                    else if (k == 10) v = b_ih[orow] + b_hh[orow];
                    else if (k == 11) v = W_ih[orow];
                } else if (G == 2 && tau == 2) {           // head a0..a3
                    if (k < 10)       v = W1[eg * 10 + k];
                    else if (k == 10) v = b1[eg];
                } else if (G == 2 && tau == 3) {           // head a4
                    if (eg == 0) {
                        if (k < 10)       v = W1[40 + k];
                        else if (k == 10) v = b1[4];
                    }
                }
                *avp[e] = v;
            }
            h4 a;
            a[0] = (_Float16)av0; a[1] = (_Float16)av1;
            a[2] = (_Float16)av2; a[3] = (_Float16)av3;
            Afrag[tau] = a;
        }
    }

    // ---- this lane's sequence values (4x redundant across g-groups; L1 serves) ----
    float vals[TT];
    {
        const float4* vrow = reinterpret_cast<const float4*>(values + (size_t)seq * TT);
        #pragma unroll
        for (int i = 0; i < TT / 4; ++i) {
            float4 v = vrow[i];
            vals[4 * i + 0] = v.x; vals[4 * i + 1] = v.y;
            vals[4 * i + 2] = v.z; vals[4 * i + 3] = v.w;
        }
        if (dir != 0) {
            #pragma unroll
            for (int i = 0; i < TT / 2; ++i) {
                float tmp = vals[i]; vals[i] = vals[TT - 1 - i]; vals[TT - 1 - i] = tmp;
            }
        }
    }

    // head scalars (wave-uniform -> SGPR)
    const float w2_0 = W2[0], w2_1 = W2[1], w2_2 = W2[2], w2_3 = W2[3], w2_4 = W2[4];
    const float b2s = b2[0];

    float c[4]  = {0.f, 0.f, 0.f, 0.f};   // c of unit 4g+tau (garbage on head slots, inert)
    float hn[4] = {0.f, 0.f, 0.f, 0.f};   // h_new of unit 4g+tau
    float sc[TT];

    #pragma unroll
    for (int t = 0; t < TT; ++t) {
        const float xt = vals[t];

        // ---- B fragment: [h; 1; x] in f16 (element-wise casts; compiler packs) ----
        const float b2f = (g == 2) ? 1.0f : hn[2];
        const float b3f = (g == 2) ? xt   : hn[3];
        h4 B;
        B[0] = (_Float16)hn[0];
        B[1] = (_Float16)hn[1];
        B[2] = (_Float16)b2f;
        B[3] = (_Float16)b3f;

        // ---- all gates + head pre-activations in 4 MFMAs ----
        const f4 z4 = {0.f, 0.f, 0.f, 0.f};
        f4 acc0 = MFMA16(Afrag[0], B, z4);
        f4 acc1 = MFMA16(Afrag[1], B, z4);
        f4 acc2 = MFMA16(Afrag[2], B, z4);
        f4 acc3 = MFMA16(Afrag[3], B, z4);

        // ---- score head (real on g==2 lanes; harmless elsewhere) ----
        {
            float z = b2s;
            float a0 = acc2[0]; a0 = fmaxf(a0, 0.2f * a0); z = fmaf(a0, w2_0, z);
            float a1 = acc2[1]; a1 = fmaxf(a1, 0.2f * a1); z = fmaf(a1, w2_1, z);
            float a2 = acc2[2]; a2 = fmaxf(a2, 0.2f * a2); z = fmaf(a2, w2_2, z);
            float a3 = acc2[3]; a3 = fmaxf(a3, 0.2f * a3); z = fmaf(a3, w2_3, z);
            float a4 = acc3[0]; a4 = fmaxf(a4, 0.2f * a4); z = fmaf(a4, w2_4, z);
            sc[t] = frcp(1.0f + fexp2(z * (-L2E)));
        }

        // ---- activations: 4 units per lane (i,f,g,o in the 4 acc regs) ----
        #pragma unroll
        for (int tau = 0; tau < 4; ++tau) {
            const f4 acc = (tau == 0) ? acc0 : (tau == 1) ? acc1 : (tau == 2) ? acc2 : acc3;
            const float gi = acc[0], gf = acc[1], gg = acc[2], go = acc[3];
            const float ef = fexp2(gf * (-L2E));
            const float ei = fexp2(gi * (-L2E));
            const float eg2 = fexp2(gg * (2.0f * L2E));
            const float t1 = 1.0f + ef, t2 = 1.0f + ei;
            const float t3 = eg2 + 1.0f, t4 = eg2 - 1.0f;
            const float t5 = t2 * t3;
            const float cn = fmaf(c[tau], t5, t4 * t1) * frcp(t1 * t5);
            c[tau] = cn;
            const float eo = fexp2(go * (-L2E));
            const float ec = fexp2(cn * (2.0f * L2E));
            hn[tau] = (ec - 1.0f) * frcp((1.0f + eo) * (ec + 1.0f));
        }
    }

    // ---- scores: g==2 lanes own the real score row; contiguous 80B stores ----
    if (g == 2) {
        float4* o4 = reinterpret_cast<float4*>(out + (size_t)seq * TT);
        #pragma unroll
        for (int i = 0; i < TT / 4; ++i) {
            float4 v;
            v.x = sc[4 * i + 0]; v.y = sc[4 * i + 1];
            v.z = sc[4 * i + 2]; v.w = sc[4 * i + 3];
            o4[i] = v;
        }
    }

    // ---- masks pass-through: g==0 lanes ----
    if (g == 0) {
        const float* mrow = masks + (size_t)seq * TT;
        float* mout = out + (size_t)BB * TT + (size_t)seq * TT;
        if (dir == 0) {
            const float4* m4 = (const float4*)mrow;
            float4* o4 = (float4*)mout;
            #pragma unroll
            for (int i = 0; i < TT / 4; ++i) o4[i] = m4[i];
        } else {
            #pragma unroll
            for (int t = 0; t < TT; ++t) mout[t] = mrow[TT - 1 - t];
        }
    }
}

extern "C" void kernel_launch(void* const* d_in, const int* in_sizes, int n_in,
                              void* d_out, int out_size, void* d_ws, size_t ws_size,
                              hipStream_t stream) {
    const float* values = (const float*)d_in[0];
    const float* masks  = (const float*)d_in[1];
    const float* W_ih   = (const float*)d_in[2];
    const float* W_hh   = (const float*)d_in[3];
    const float* b_ih   = (const float*)d_in[4];
    const float* b_hh   = (const float*)d_in[5];
    const float* W1     = (const float*)d_in[6];
    const float* b1     = (const float*)d_in[7];
    const float* W2     = (const float*)d_in[8];
    const float* b2     = (const float*)d_in[9];
    const int*   direct = (const int*)d_in[11];
    float* out = (float*)d_out;

    // 16 sequences per wave, 4 waves per block
    const int block = 256;
    const int grid = BB / 64;   // 4096 blocks -> 16384 waves -> 262144 seqs
    lstm_disc_mfma<<<grid, block, 0, stream>>>(values, masks, W_ih, W_hh, b_ih, b_hh,
                                               W1, b1, W2, b2, direct, out);
}

// Round 9
// 79.909 us; speedup vs baseline: 28.2984x; 1.2824x over previous
//
#include <hip/hip_runtime.h>

#define BB 262144
#define TT 20
#define HH 10

static constexpr float L2E = 1.44269504088896340736f;

typedef float    f4 __attribute__((ext_vector_type(4)));
typedef _Float16 h4 __attribute__((ext_vector_type(4)));

#define MFMA16(A, B, C) __builtin_amdgcn_mfma_f32_16x16x16f16((A), (B), (C), 0, 0, 0)

__device__ __forceinline__ float frcp(float x)  { return __builtin_amdgcn_rcpf(x); }
__device__ __forceinline__ float fexp2(float x) { return __builtin_amdgcn_exp2f(x); }

// Slot map (unit handled by lane-group g, MFMA tile tau):
//   g0: u0,u1,u2 | g1: u4,u5,u6 | g2: u8,u9,u3 | g3: u7, headA(a0..3), headB(a4)
// A rows pre-scaled: gates i,f,o by -L2E, gate g by +2*L2E (head rows unscaled).
// B (k = 4g+e, col = s): g0: h0..h3, g1: h4..h7, g2: h8,h9,1,x, g3: dc (A k>=12 == 0).
// h3 (computed on g2.tau2) and h7 (g3.tau0) return via one shfl_xor(32).
// C: lane(g,s) tile tau regs 0..3 = scaled gates i,f,g,o of smap[g][tau].
__global__ __launch_bounds__(256) void lstm_disc_mfma(
    const float* __restrict__ values, const float* __restrict__ masks,
    const float* __restrict__ W_ih, const float* __restrict__ W_hh,
    const float* __restrict__ b_ih, const float* __restrict__ b_hh,
    const float* __restrict__ W1, const float* __restrict__ b1,
    const float* __restrict__ W2, const float* __restrict__ b2,
    const int* __restrict__ directp,
    float* __restrict__ out)
{
    const int tid = threadIdx.x;
    const int l   = tid & 63;
    const int g   = l >> 4;    // B/C k-window group; A k-window
    const int s   = l & 15;    // seq within wave (B/C col); A row
    const int gw  = blockIdx.x * 4 + (tid >> 6);
    const int seq = gw * 16 + s;
    const int dir = *directp;
    const bool gIs2 = (g == 2);
    const bool gIs3 = (g == 3);

    // ---- build A fragments once (per-lane scattered loads; one-time cost) ----
    h4 Af0, Af1, Af2;
    {
        const int r  = s;          // A row = l&15
        const int G  = r >> 2;     // slot group of this row
        const int e  = r & 3;      // gate index / head row
        const int kb = g * 4;      // k-window base
        h4* afp[3] = {&Af0, &Af1, &Af2};
        #pragma unroll
        for (int tau = 0; tau < 3; ++tau) {
            // unit id for (G,tau); -1 = headA, -2 = headB
            int u;
            if (tau == 0)      u = (G == 0) ? 0 : (G == 1) ? 4 : (G == 2) ? 8 : 7;
            else if (tau == 1) u = (G == 0) ? 1 : (G == 1) ? 5 : (G == 2) ? 9 : -1;
            else               u = (G == 0) ? 2 : (G == 1) ? 6 : (G == 2) ? 3 : -2;
            float av0 = 0.f, av1 = 0.f, av2 = 0.f, av3 = 0.f;
            float* avp[4] = {&av0, &av1, &av2, &av3};
            #pragma unroll
            for (int e4 = 0; e4 < 4; ++e4) {
                const int k = kb + e4;
                float v = 0.0f;
                if (u >= 0) {                              // LSTM unit row
                    const int orow = 10 * e + u;           // gate e of unit u
                    if (k < 10)       v = W_hh[orow * 10 + k];
                    else if (k == 10) v = b_ih[orow] + b_hh[orow];
                    else if (k == 11) v = W_ih[orow];
                    v *= (e == 2) ? (2.0f * L2E) : (-L2E); // prescale for exp2
                } else if (u == -1) {                      // head rows a0..a3
                    if (k < 10)       v = W1[e * 10 + k];
                    else if (k == 10) v = b1[e];
                } else {                                   // head row a4 (e==0 only)
                    if (e == 0) {
                        if (k < 10)       v = W1[40 + k];
                        else if (k == 10) v = b1[4];
                    }
                }
                *avp[e4] = v;
            }
            h4 a;
            a[0] = (_Float16)av0; a[1] = (_Float16)av1;
            a[2] = (_Float16)av2; a[3] = (_Float16)av3;
            *afp[tau] = a;
        }
    }

    // ---- this lane's sequence values ----
    float vals[TT];
    {
        const float4* vrow = reinterpret_cast<const float4*>(values + (size_t)seq * TT);
        #pragma unroll
        for (int i = 0; i < TT / 4; ++i) {
            float4 v = vrow[i];
            vals[4 * i + 0] = v.x; vals[4 * i + 1] = v.y;
            vals[4 * i + 2] = v.z; vals[4 * i + 3] = v.w;
        }
        if (dir != 0) {
            #pragma unroll
            for (int i = 0; i < TT / 2; ++i) {
                float tmp = vals[i]; vals[i] = vals[TT - 1 - i]; vals[TT - 1 - i] = tmp;
            }
        }
    }

    // head scalars, prescaled by -L2E (wave-uniform -> SGPR)
    const float w2p0 = -L2E * W2[0], w2p1 = -L2E * W2[1], w2p2 = -L2E * W2[2],
                w2p3 = -L2E * W2[3], w2p4 = -L2E * W2[4];
    const float b2p = -L2E * b2[0];

    float c0 = 0.f, c1 = 0.f, c2 = 0.f;      // cell states of smap[g][0..2]
    float hA = 0.f, hB = 0.f, hC = 0.f;      // h_new of smap[g][0..2]
    float sc[TT];

    // activation: ACC = (-L2E*i, -L2E*f, 2L2E*g, -L2E*o); 5 exp2 + 2 rcp, 15 VALU
#define ACT(ACC, CC, HN) { \
        const float ei  = fexp2(ACC[0]); \
        const float ef  = fexp2(ACC[1]); \
        const float eg2 = fexp2(ACC[2]); \
        const float eo  = fexp2(ACC[3]); \
        const float t1 = 1.0f + ef, t2 = 1.0f + ei; \
        const float t3 = eg2 + 1.0f, t4 = eg2 - 1.0f; \
        const float t5 = t2 * t3; \
        const float cn = fmaf((CC), t5, t4 * t1) * frcp(t1 * t5); \
        (CC) = cn; \
        const float ec = fexp2(cn * (2.0f * L2E)); \
        (HN) = (ec - 1.0f) * frcp((1.0f + eo) * (ec + 1.0f)); \
    }

    #pragma unroll
    for (int t = 0; t < TT; ++t) {
        const float xt = vals[t];

        // ---- B fragment: local h + one cross-pair shuffle for h3/h7 ----
        const float msg = gIs3 ? hA : hC;            // g2 sends u3.h, g3 sends u7.h
        const float rsw = __shfl_xor(msg, 32, 64);   // g0<->g2, g1<->g3
        const float B2f = gIs2 ? 1.0f : hC;
        const float B3f = gIs2 ? xt   : rsw;
        h4 Bf;
        Bf[0] = (_Float16)hA; Bf[1] = (_Float16)hB;
        Bf[2] = (_Float16)B2f; Bf[3] = (_Float16)B3f;

        // ---- gates + head pre-activations in 3 MFMAs ----
        const f4 z4 = {0.f, 0.f, 0.f, 0.f};
        f4 acc0 = MFMA16(Af0, Bf, z4);
        f4 acc1 = MFMA16(Af1, Bf, z4);
        f4 acc2 = MFMA16(Af2, Bf, z4);

        // ---- score head (real on g3 lanes: acc1 = a0..a3, acc2[0] = a4) ----
        {
            float zz = b2p;
            float a0 = acc1[0]; a0 = fmaxf(a0, 0.2f * a0); zz = fmaf(a0, w2p0, zz);
            float a1 = acc1[1]; a1 = fmaxf(a1, 0.2f * a1); zz = fmaf(a1, w2p1, zz);
            float a2 = acc1[2]; a2 = fmaxf(a2, 0.2f * a2); zz = fmaf(a2, w2p2, zz);
            float a3 = acc1[3]; a3 = fmaxf(a3, 0.2f * a3); zz = fmaf(a3, w2p3, zz);
            float a4 = acc2[0]; a4 = fmaxf(a4, 0.2f * a4); zz = fmaf(a4, w2p4, zz);
            sc[t] = frcp(1.0f + fexp2(zz));          // zz already = -L2E * logit
        }

        // ---- activations: 3 units per lane (garbage-but-bounded on head slots) ----
        ACT(acc0, c0, hA)
        ACT(acc1, c1, hB)
        ACT(acc2, c2, hC)
    }

    // ---- scores: g3 lanes own the real score row ----
    if (gIs3) {
        float4* o4 = reinterpret_cast<float4*>(out + (size_t)seq * TT);
        #pragma unroll
        for (int i = 0; i < TT / 4; ++i) {
            float4 v;
            v.x = sc[4 * i + 0]; v.y = sc[4 * i + 1];
            v.z = sc[4 * i + 2]; v.w = sc[4 * i + 3];
            o4[i] = v;
        }
    }

    // ---- masks pass-through: g0 lanes ----
    if (g == 0) {
        const float* mrow = masks + (size_t)seq * TT;
        float* mout = out + (size_t)BB * TT + (size_t)seq * TT;
        if (dir == 0) {
            const float4* m4 = (const float4*)mrow;
            float4* o4 = (float4*)mout;
            #pragma unroll
            for (int i = 0; i < TT / 4; ++i) o4[i] = m4[i];
        } else {
            #pragma unroll
            for (int t = 0; t < TT; ++t) mout[t] = mrow[TT - 1 - t];
        }
    }
#undef ACT
}

extern "C" void kernel_launch(void* const* d_in, const int* in_sizes, int n_in,
                              void* d_out, int out_size, void* d_ws, size_t ws_size,
                              hipStream_t stream) {
    const float* values = (const float*)d_in[0];
    const float* masks  = (const float*)d_in[1];
    const float* W_ih   = (const float*)d_in[2];
    const float* W_hh   = (const float*)d_in[3];
    const float* b_ih   = (const float*)d_in[4];
    const float* b_hh   = (const float*)d_in[5];
    const float* W1     = (const float*)d_in[6];
    const float* b1     = (const float*)d_in[7];
    const float* W2     = (const float*)d_in[8];
    const float* b2     = (const float*)d_in[9];
    const int*   direct = (const int*)d_in[11];
    float* out = (float*)d_out;

    // 16 sequences per wave, 4 waves per block
    const int block = 256;
    const int grid = BB / 64;   // 4096 blocks -> 16384 waves -> 262144 seqs
    lstm_disc_mfma<<<grid, block, 0, stream>>>(values, masks, W_ih, W_hh, b_ih, b_hh,
                                               W1, b1, W2, b2, direct, out);
}